// Round 16
// baseline (931.822 us; speedup 1.0000x reference)
//
#include <hip/hip_runtime.h>
#include <hip/hip_cooperative_groups.h>
#include <hip/hip_fp8.h>
#include <math.h>

#define NN 10000
#define NE 320000
#define DD 256
#define KSEL 8000
#define KK 512
#define NPART 157
#define NB 1024            // cooperative build grid (4 blocks/CU, co-resident)

typedef unsigned int uint;
typedef unsigned short ushort;
typedef unsigned char uchar;
typedef __attribute__((ext_vector_type(8))) short short8;
typedef __attribute__((ext_vector_type(4))) float f32x4;
typedef __attribute__((ext_vector_type(4))) ushort us4;
typedef __attribute__((ext_vector_type(8))) ushort us8;

namespace cg = cooperative_groups;

__device__ __forceinline__ uint encodeF(float f) {
    uint u = __float_as_uint(f);
    return (u & 0x80000000u) ? ~u : (u | 0x80000000u);
}

__device__ __forceinline__ ushort f2bf(float f) {
    uint u = __float_as_uint(f);
    u += 0x7FFFu + ((u >> 16) & 1u);
    return (ushort)(u >> 16);
}

__device__ __forceinline__ float fp8dec(uint b) {
    __hip_fp8_e4m3 t;
    t.__x = (__hip_fp8_storage_t)b;
    return (float)t;
}
__device__ __forceinline__ uint fp8enc(float f) {
    return (uint)__hip_fp8_e4m3(f).__x;
}

// ============ 1. build: zero + casts + count + scan + fill + mean =========
// One cooperative kernel, 5 phases separated by grid.sync().
#define WB 32
#define QH (NN * 64)
__global__ __launch_bounds__(256) void build(
    const float* __restrict__ h, const float* __restrict__ W_l,
    const float* __restrict__ W_r, const int* __restrict__ ei,
    ushort* __restrict__ Ab, uchar* __restrict__ h8,
    ushort* __restrict__ Wt, int* __restrict__ degi,
    int* __restrict__ rank, int* __restrict__ start,
    float* __restrict__ invdeg, int* __restrict__ csr,
    uint* __restrict__ cnt) {
    cg::grid_group g = cg::this_grid();
    __shared__ float tile[64][65];
    __shared__ int wsum[4], woff[4];
    const int b = blockIdx.x, t = threadIdx.x;
    const int gt = b * 256 + t;
    const int GSTRIDE = NB * 256;

    // ---- Phase A: zero degi/cnt; W-transpose (blocks 0..31); h casts -----
    for (int i = gt; i < NN; i += GSTRIDE) degi[i] = 0;
    if (gt == 0) cnt[0] = 0;
    if (b < WB) {
        const int tr = b >> 2, tc = b & 3;
        const int k0 = tr * 64, n0 = tc * 64;
        const int r = t >> 6, c = t & 63;
        const float* Wsrc = (k0 < 256) ? (W_l + (size_t)k0 * DD)
                                       : (W_r + (size_t)(k0 - 256) * DD);
#pragma unroll
        for (int i = 0; i < 16; i++) {
            int row = r + i * 4;
            tile[row][c] = Wsrc[(size_t)row * DD + n0 + c];
        }
        __syncthreads();
#pragma unroll
        for (int i = 0; i < 16; i++) {
            int row = r + i * 4;
            Wt[(size_t)(n0 + row) * KK + k0 + c] = f2bf(tile[c][row]);
        }
    }
    for (int id = gt; id < QH; id += GSTRIDE) {
        int node = id >> 6, seg = (id & 63) * 4;
        float4 v = *(const float4*)(h + (size_t)node * DD + seg);
        us4 o;
        o[0] = f2bf(v.x); o[1] = f2bf(v.y); o[2] = f2bf(v.z); o[3] = f2bf(v.w);
        *(us4*)(Ab + (size_t)node * KK + 256 + seg) = o;
        uint pk = fp8enc(v.x) | (fp8enc(v.y) << 8)
                | (fp8enc(v.z) << 16) | (fp8enc(v.w) << 24);
        *(uint*)(h8 + (size_t)node * DD + seg) = pk;
    }
    __threadfence();
    g.sync();

    // ---- Phase B: degree count + edge rank -------------------------------
    for (int e = gt; e < NE; e += GSTRIDE)
        rank[e] = atomicAdd(&degi[ei[NE + e]], 1);
    __threadfence();
    g.sync();

    // ---- Phase C: prefix scan (block 0 only, 256 threads, CH=40) ---------
    if (b == 0) {
        const int CH = 40;                 // 256*40 = 10240 >= NN
        const int lane = t & 63, w4 = t >> 6;
        const int base = t * CH;
        int sum = 0;
#pragma unroll
        for (int i = 0; i < CH; i++) {
            int idx = base + i;
            if (idx < NN) sum += degi[idx];
        }
        int x = sum;
#pragma unroll
        for (int off = 1; off < 64; off <<= 1) {
            int v = __shfl_up(x, off);
            if (lane >= off) x += v;
        }
        if (lane == 63) wsum[w4] = x;
        __syncthreads();
        if (t == 0) {
            int run = 0;
#pragma unroll
            for (int w = 0; w < 4; w++) { woff[w] = run; run += wsum[w]; }
        }
        __syncthreads();
        int run = woff[w4] + x - sum;
#pragma unroll
        for (int i = 0; i < CH; i++) {
            int idx = base + i;
            if (idx < NN) {
                start[idx] = run;
                int d = degi[idx];
                invdeg[idx] = 1.0f / fmaxf((float)d, 1.0f);
                run += d;
            }
        }
        if (t == 255) start[NN] = NE;
    }
    __threadfence();
    g.sync();

    // ---- Phase D: fill CSR (atomic-free, rank-addressed) -----------------
    for (int e = gt; e < NE; e += GSTRIDE)
        csr[start[ei[NE + e]] + rank[e]] = ei[e];
    __threadfence();
    g.sync();

    // ---- Phase E: gather mean (fp8 reads, L2-resident) -------------------
    const int lane = t & 63;
    for (int grp = b; grp < (NN + 3) / 4; grp += NB) {
        int node = grp * 4 + (t >> 6);
        if (node >= NN) continue;
        int s = start[node], e = start[node + 1];
        const uchar* hp = h8 + lane * 4;
        float a0 = 0.f, a1 = 0.f, a2 = 0.f, a3 = 0.f;
        float b0 = 0.f, b1 = 0.f, b2 = 0.f, b3 = 0.f;
        int j = s;
        for (; j + 4 <= e; j += 4) {
            int s0 = csr[j], s1 = csr[j + 1], s2 = csr[j + 2], s3 = csr[j + 3];
            uint w0 = *(const uint*)(hp + (size_t)s0 * DD);
            uint w1 = *(const uint*)(hp + (size_t)s1 * DD);
            uint w2 = *(const uint*)(hp + (size_t)s2 * DD);
            uint w3 = *(const uint*)(hp + (size_t)s3 * DD);
            a0 += fp8dec(w0 & 0xFF) + fp8dec(w1 & 0xFF);
            a1 += fp8dec((w0 >> 8) & 0xFF) + fp8dec((w1 >> 8) & 0xFF);
            a2 += fp8dec((w0 >> 16) & 0xFF) + fp8dec((w1 >> 16) & 0xFF);
            a3 += fp8dec(w0 >> 24) + fp8dec(w1 >> 24);
            b0 += fp8dec(w2 & 0xFF) + fp8dec(w3 & 0xFF);
            b1 += fp8dec((w2 >> 8) & 0xFF) + fp8dec((w3 >> 8) & 0xFF);
            b2 += fp8dec((w2 >> 16) & 0xFF) + fp8dec((w3 >> 16) & 0xFF);
            b3 += fp8dec(w2 >> 24) + fp8dec(w3 >> 24);
        }
        for (; j < e; j++) {
            uint w0 = *(const uint*)(hp + (size_t)csr[j] * DD);
            a0 += fp8dec(w0 & 0xFF);
            a1 += fp8dec((w0 >> 8) & 0xFF);
            a2 += fp8dec((w0 >> 16) & 0xFF);
            a3 += fp8dec(w0 >> 24);
        }
        float id = invdeg[node];
        us4 m;
        m[0] = f2bf((a0 + b0) * id);
        m[1] = f2bf((a1 + b1) * id);
        m[2] = f2bf((a2 + b2) * id);
        m[3] = f2bf((a3 + b3) * id);
        *(us4*)(Ab + (size_t)node * KK + lane * 4) = m;
    }
}

// ---------------- 2. MFMA GEMM: atomic-free y/c/r via LDS reduce ----------
__global__ __launch_bounds__(256) void gemm_x(
    const ushort* __restrict__ Ab, const ushort* __restrict__ Wt,
    const float* __restrict__ b_l,
    const float* __restrict__ W_rel, const float* __restrict__ W_gate,
    const float* __restrict__ W_root,
    float* __restrict__ xout, float* __restrict__ y,
    float* __restrict__ cvec, float* __restrict__ rvec) {
    __shared__ ushort Asm[2][32][40];
    __shared__ ushort Bsm[2][256][40];
    __shared__ float Ys[4][32], Cs[4][32], Rs[4][32];
    const int t    = threadIdx.x;
    const int row0 = blockIdx.x * 32;
    const int wid  = t >> 6, lane = t & 63;
    const int l15  = lane & 15, g = lane >> 4;

    f32x4 acc[2][4];
#pragma unroll
    for (int fi = 0; fi < 2; fi++)
#pragma unroll
        for (int fj = 0; fj < 4; fj++) acc[fi][fj] = (f32x4)0.f;

    const int  arow = t >> 3, akseg = (t & 7) * 4;
    const bool aok  = (row0 + arow) < NN;
    const ushort* aptr = Ab + (size_t)(row0 + arow) * KK + akseg;
    const ushort* bptr = Wt + (size_t)t * KK;

    us4 areg = {0, 0, 0, 0};
    us8 breg[4];
    if (aok) areg = *(const us4*)(aptr);
#pragma unroll
    for (int jj = 0; jj < 4; jj++) breg[jj] = *(const us8*)(bptr + jj * 8);
    *(us4*)&Asm[0][arow][akseg] = areg;
#pragma unroll
    for (int jj = 0; jj < 4; jj++) *(us8*)&Bsm[0][t][jj * 8] = breg[jj];
    __syncthreads();

    for (int ks = 0; ks < 16; ++ks) {
        const int cur = ks & 1;
        if (ks < 15) {
            const int k0 = (ks + 1) * 32;
            if (aok) areg = *(const us4*)(aptr + k0);
#pragma unroll
            for (int jj = 0; jj < 4; jj++) breg[jj] = *(const us8*)(bptr + k0 + jj * 8);
        }
        short8 af0 = *(const short8*)&Asm[cur][l15][g * 8];
        short8 af1 = *(const short8*)&Asm[cur][16 + l15][g * 8];
#pragma unroll
        for (int fj = 0; fj < 4; fj++) {
            short8 bf = *(const short8*)&Bsm[cur][wid * 64 + fj * 16 + l15][g * 8];
            acc[0][fj] = __builtin_amdgcn_mfma_f32_16x16x32_bf16(af0, bf, acc[0][fj], 0, 0, 0);
            acc[1][fj] = __builtin_amdgcn_mfma_f32_16x16x32_bf16(af1, bf, acc[1][fj], 0, 0, 0);
        }
        if (ks < 15) {
            const int nb = cur ^ 1;
            *(us4*)&Asm[nb][arow][akseg] = areg;
#pragma unroll
            for (int jj = 0; jj < 4; jj++) *(us8*)&Bsm[nb][t][jj * 8] = breg[jj];
        }
        __syncthreads();
    }

    const int wcol0 = wid * 64;
    float bl[4], wl[4], wg[4], wo[4];
#pragma unroll
    for (int fj = 0; fj < 4; fj++) {
        int col = wcol0 + fj * 16 + l15;
        bl[fj] = b_l[col]; wl[fj] = W_rel[col];
        wg[fj] = W_gate[col]; wo[fj] = W_root[col];
    }
#pragma unroll
    for (int fi = 0; fi < 2; fi++) {
#pragma unroll
        for (int r = 0; r < 4; r++) {
            int row = row0 + fi * 16 + g * 4 + r;
            float py = 0.f, pc = 0.f, pr = 0.f;
#pragma unroll
            for (int fj = 0; fj < 4; fj++) {
                float v = fmaxf(acc[fi][fj][r] + bl[fj], 0.f);
                if (row < NN)
                    xout[(size_t)row * DD + wcol0 + fj * 16 + l15] = v;
                py = fmaf(v, wl[fj], py);
                pc = fmaf(v, wg[fj], pc);
                pr = fmaf(v, wo[fj], pr);
            }
#pragma unroll
            for (int off = 1; off < 16; off <<= 1) {
                py += __shfl_xor(py, off);
                pc += __shfl_xor(pc, off);
                pr += __shfl_xor(pr, off);
            }
            if (l15 == 0) {
                int rl = fi * 16 + g * 4 + r;
                Ys[wid][rl] = py; Cs[wid][rl] = pc; Rs[wid][rl] = pr;
            }
        }
    }
    __syncthreads();
    if (t < 32) {
        int row = row0 + t;
        if (row < NN) {
            y[row]    = Ys[0][t] + Ys[1][t] + Ys[2][t] + Ys[3][t];
            cvec[row] = Cs[0][t] + Cs[1][t] + Cs[2][t] + Cs[3][t];
            rvec[row] = Rs[0][t] + Rs[1][t] + Rs[2][t] + Rs[3][t];
        }
    }
}

// ---------------- 3. gather y + score + key -------------------------------
__global__ __launch_bounds__(256) void gather_score(
    const float* __restrict__ y, const float* __restrict__ r,
    const float* __restrict__ b_rel, const int* __restrict__ csr,
    const int* __restrict__ start,
    float* __restrict__ score, uint* __restrict__ key) {
    int gt   = blockIdx.x * 256 + threadIdx.x;
    int node = gt >> 4, l = gt & 15;
    if (node >= NN) return;
    int s = start[node], e = start[node + 1];
    float acc = 0.f;
    for (int j = s + l; j < e; j += 16) acc += y[csr[j]];
#pragma unroll
    for (int o = 8; o; o >>= 1) acc += __shfl_xor(acc, o, 16);
    if (l == 0) {
        float sc = tanhf(acc + b_rel[0] + r[node]);
        score[node] = sc;
        key[node]   = encodeF(sc);
    }
}

// ---------------- 4. radix select v2 --------------------------------------
__global__ __launch_bounds__(1024) void radix_select(
    const uint* __restrict__ key, const float* __restrict__ score,
    const float* __restrict__ cvec,
    float* __restrict__ wsc, float* __restrict__ denom) {
    __shared__ uint  hist[16][260];
    __shared__ uint  sh_prefix, sh_need;
    __shared__ float wred[16];
    __shared__ uint  tick_s;
    const int t = threadIdx.x, wid = t >> 6, lane = t & 63;

    uint  myk[10];
    float mys[10], myl[10];
#pragma unroll
    for (int i = 0; i < 10; i++) {
        int idx = t + i * 1024;
        if (idx < NN) {
            uint k  = key[idx];
            float s = score[idx];
            myk[i] = k; mys[i] = s; myl[i] = s * cvec[idx];
        } else {
            myk[i] = 0u; mys[i] = 0.f; myl[i] = -INFINITY;
        }
    }

    uint prefix = 0, pmask = 0, need = KSEL;
    float vmax = -INFINITY;
    for (int shift = 24; shift >= 0; shift -= 8) {
        for (int i = lane; i < 256; i += 64) hist[wid][i] = 0;
        if (shift == 0) {
#pragma unroll
            for (int i = 0; i < 10; i++) {
                uint k = myk[i];
                if ((k & pmask) == prefix) atomicAdd(&hist[wid][k & 255], 1u);
                if (k >= prefix) vmax = fmaxf(vmax, myl[i]);
            }
        } else {
#pragma unroll
            for (int i = 0; i < 10; i++) {
                uint k = myk[i];
                if ((k & pmask) == prefix)
                    atomicAdd(&hist[wid][(k >> shift) & 255], 1u);
            }
        }
        __syncthreads();
        if (wid == 0) {
            uint4 a = make_uint4(0u, 0u, 0u, 0u);
#pragma unroll
            for (int w = 0; w < 16; w++) {
                uint4 v = *(const uint4*)&hist[w][lane * 4];
                a.x += v.x; a.y += v.y; a.z += v.z; a.w += v.w;
            }
            uint s3 = a.w, s2 = a.z + s3, s1 = a.y + s2, s0 = a.x + s1;
            uint x = s0;
#pragma unroll
            for (int off = 1; off < 64; off <<= 1) {
                uint v = __shfl_down(x, off);
                if (lane + off < 64) x += v;
            }
            uint excl = x - s0;
            uint hi0 = excl + s0, hi1 = excl + s1;
            uint hi2 = excl + s2, hi3 = excl + s3;
            if (need <= hi0 && need > hi0 - a.x) {
                sh_prefix = prefix | ((uint)(lane * 4 + 0) << shift);
                sh_need   = need - (hi0 - a.x);
            }
            if (need <= hi1 && need > hi1 - a.y) {
                sh_prefix = prefix | ((uint)(lane * 4 + 1) << shift);
                sh_need   = need - (hi1 - a.y);
            }
            if (need <= hi2 && need > hi2 - a.z) {
                sh_prefix = prefix | ((uint)(lane * 4 + 2) << shift);
                sh_need   = need - (hi2 - a.z);
            }
            if (need <= hi3 && need > hi3 - a.w) {
                sh_prefix = prefix | ((uint)(lane * 4 + 3) << shift);
                sh_need   = need - (hi3 - a.w);
            }
        }
        __syncthreads();
        prefix = sh_prefix;
        need   = sh_need;
        pmask |= (0xFFu << shift);
    }
    const uint T      = prefix;
    const uint needEq = need;
#pragma unroll
    for (int o = 32; o; o >>= 1) vmax = fmaxf(vmax, __shfl_xor(vmax, o));
    if (lane == 0) wred[wid] = vmax;
    if (t == 0) tick_s = 0;
    __syncthreads();
    float m = wred[0];
#pragma unroll
    for (int w = 1; w < 16; w++) m = fmaxf(m, wred[w]);
    __syncthreads();
    float dsum = 0.f;
#pragma unroll
    for (int i = 0; i < 10; i++) {
        int idx = t + i * 1024;
        if (idx >= NN) continue;
        uint k = myk[i];
        bool selm = (k > T);
        if (k == T) selm = (atomicAdd(&tick_s, 1u) < needEq);
        float wv = 0.f;
        if (selm) {
            float w = expf(myl[i] - m);
            wv   = w * mys[i];
            dsum += w;
        }
        wsc[idx] = wv;
    }
#pragma unroll
    for (int o = 32; o; o >>= 1) dsum += __shfl_xor(dsum, o);
    if (lane == 0) wred[wid] = dsum;
    __syncthreads();
    if (t == 0) {
        float d = 0.f;
#pragma unroll
        for (int w = 0; w < 16; w++) d += wred[w];
        denom[0] = d;
    }
}

// ---------------- 5. weighted row-sum + last-block finalize ---------------
__global__ __launch_bounds__(256) void reduce_rows(
    const float* __restrict__ x, const float* __restrict__ wsc,
    float* __restrict__ part, uint* __restrict__ counter,
    const float* __restrict__ denom, float* __restrict__ out) {
    __shared__ float red[3][DD];
    __shared__ uint  lastdone;
    const int wave = threadIdx.x >> 6;
    const int lane = threadIdx.x & 63;
    const int row0 = (blockIdx.x * 4 + wave) * 16;
    const float* xp = x + lane * 4;
    float4 acc = make_float4(0.f, 0.f, 0.f, 0.f);
    if (row0 < NN) {
#pragma unroll
        for (int rb = 0; rb < 16; rb += 4) {
            int r0 = row0 + rb;
            float w0 = wsc[r0 + 0], w1 = wsc[r0 + 1];
            float w2 = wsc[r0 + 2], w3 = wsc[r0 + 3];
            float4 v0 = *(const float4*)(xp + (size_t)(r0 + 0) * DD);
            float4 v1 = *(const float4*)(xp + (size_t)(r0 + 1) * DD);
            float4 v2 = *(const float4*)(xp + (size_t)(r0 + 2) * DD);
            float4 v3 = *(const float4*)(xp + (size_t)(r0 + 3) * DD);
            acc.x = fmaf(w0, v0.x, fmaf(w1, v1.x, fmaf(w2, v2.x, fmaf(w3, v3.x, acc.x))));
            acc.y = fmaf(w0, v0.y, fmaf(w1, v1.y, fmaf(w2, v2.y, fmaf(w3, v3.y, acc.y))));
            acc.z = fmaf(w0, v0.z, fmaf(w1, v1.z, fmaf(w2, v2.z, fmaf(w3, v3.z, acc.z))));
            acc.w = fmaf(w0, v0.w, fmaf(w1, v1.w, fmaf(w2, v2.w, fmaf(w3, v3.w, acc.w))));
        }
    }
    if (wave > 0) *(float4*)&red[wave - 1][lane * 4] = acc;
    __syncthreads();
    if (wave == 0) {
#pragma unroll
        for (int w = 0; w < 3; w++) {
            float4 rv = *(float4*)&red[w][lane * 4];
            acc.x += rv.x; acc.y += rv.y; acc.z += rv.z; acc.w += rv.w;
        }
        *(float4*)(part + (size_t)blockIdx.x * DD + lane * 4) = acc;
    }
    __threadfence();
    if (threadIdx.x == 0) lastdone = atomicAdd(counter, 1u);
    __syncthreads();
    if (lastdone == NPART - 1) {
        __threadfence();
        int i = threadIdx.x;
        float s = 0.f;
        for (int b = 0; b < NPART; b++) s += part[(size_t)b * DD + i];
        out[i] = s / denom[0];
    }
}

extern "C" void kernel_launch(void* const* d_in, const int* in_sizes, int n_in,
                              void* d_out, int out_size, void* d_ws, size_t ws_size,
                              hipStream_t stream) {
    const float* h      = (const float*)d_in[0];
    const int*   ei     = (const int*)d_in[1];
    const float* W_l    = (const float*)d_in[2];
    const float* b_l    = (const float*)d_in[3];
    const float* W_r    = (const float*)d_in[4];
    const float* W_rel  = (const float*)d_in[5];
    const float* b_rel  = (const float*)d_in[6];
    const float* W_root = (const float*)d_in[7];
    const float* W_gate = (const float*)d_in[8];
    // b_gate (d_in[9]) cancels in softmax
    float* out = (float*)d_out;

    char* p = (char*)d_ws;
    auto alloc = [&p](size_t bytes) {
        char* q = p;
        p += (bytes + 63) & ~(size_t)63;
        return q;
    };
    ushort* Ab    = (ushort*)alloc((size_t)NN * KK * 2);   // [mean|h] bf16
    uchar*  h8    = (uchar*) alloc((size_t)NN * DD);
    float*  xbuf  = (float*) alloc((size_t)NN * DD * 4);
    ushort* Wt    = (ushort*)alloc((size_t)DD * KK * 2);
    int*    csr   = (int*)   alloc((size_t)NE * 4);
    int*    rank  = (int*)   alloc((size_t)NE * 4);
    int*    start = (int*)   alloc((size_t)(NN + 1) * 4);
    float*  invdeg= (float*) alloc((size_t)NN * 4);
    float*  score = (float*) alloc((size_t)NN * 4);
    uint*   key   = (uint*)  alloc((size_t)NN * 4);
    float*  wsc   = (float*) alloc((size_t)NN * 4);
    float*  denom = (float*) alloc(64);
    float*  part  = (float*) alloc((size_t)NPART * DD * 4);
    float*  y     = (float*) alloc((size_t)NN * 4);
    float*  cbuf  = (float*) alloc((size_t)NN * 4);
    float*  rbuf  = (float*) alloc((size_t)NN * 4);
    int*    degi  = (int*)   alloc((size_t)NN * 4);   // zeroed inside build
    uint*   cnt   = (uint*)  alloc(64);               // zeroed inside build

    void* bargs[] = {
        (void*)&h, (void*)&W_l, (void*)&W_r, (void*)&ei,
        (void*)&Ab, (void*)&h8, (void*)&Wt, (void*)&degi,
        (void*)&rank, (void*)&start, (void*)&invdeg, (void*)&csr,
        (void*)&cnt
    };
    hipLaunchCooperativeKernel((void*)build, dim3(NB), dim3(256),
                               bargs, 0, stream);

    gemm_x      <<<(NN + 31) / 32, 256, 0, stream>>>(Ab, Wt, b_l,
                                                     W_rel, W_gate, W_root,
                                                     xbuf, y, cbuf, rbuf);
    gather_score<<<(NN * 16 + 255) / 256, 256, 0, stream>>>(y, rbuf, b_rel, csr,
                                                            start, score, key);
    radix_select<<<1, 1024, 0, stream>>>(key, score, cbuf, wsc, denom);
    reduce_rows <<<NPART, 256, 0, stream>>>(xbuf, wsc, part, cnt, denom, out);
    (void)n_in; (void)in_sizes; (void)out_size; (void)ws_size;
}

// Round 17
// 141.324 us; speedup vs baseline: 6.5935x; 6.5935x over previous
//
#include <hip/hip_runtime.h>
#include <hip/hip_fp8.h>
#include <math.h>

#define NN 10000
#define NE 320000
#define DD 256
#define KSEL 8000
#define KK 512
#define NPART 157

typedef unsigned int uint;
typedef unsigned short ushort;
typedef unsigned char uchar;
typedef __attribute__((ext_vector_type(8))) short short8;
typedef __attribute__((ext_vector_type(4))) float f32x4;
typedef __attribute__((ext_vector_type(4))) ushort us4;
typedef __attribute__((ext_vector_type(8))) ushort us8;

__device__ __forceinline__ uint encodeF(float f) {
    uint u = __float_as_uint(f);
    return (u & 0x80000000u) ? ~u : (u | 0x80000000u);
}

__device__ __forceinline__ ushort f2bf(float f) {
    uint u = __float_as_uint(f);
    u += 0x7FFFu + ((u >> 16) & 1u);
    return (ushort)(u >> 16);
}

__device__ __forceinline__ float fp8dec(uint b) {
    __hip_fp8_e4m3 t;
    t.__x = (__hip_fp8_storage_t)b;
    return (float)t;
}
__device__ __forceinline__ uint fp8enc(float f) {
    return (uint)__hip_fp8_e4m3(f).__x;
}

// ---------------- 0. zero degi (40000 B) ----------------------------------
#define ZQUADS 2500
__global__ __launch_bounds__(256) void zero_bufs(float4* __restrict__ z) {
    int i = blockIdx.x * 256 + threadIdx.x;
    if (i < ZQUADS) z[i] = make_float4(0.f, 0.f, 0.f, 0.f);
}

// ---------------- 1. prep: W-transpose + cast_h + count_deg w/ ranks ------
#define WB 32
#define HB 2500
#define DB 1250
__global__ __launch_bounds__(256) void prep(
    const float* __restrict__ h, const float* __restrict__ W_l,
    const float* __restrict__ W_r, const int* __restrict__ ei,
    ushort* __restrict__ Ab, uchar* __restrict__ h8,
    ushort* __restrict__ Wt, int* __restrict__ degi,
    int* __restrict__ rank) {
    const int b = blockIdx.x, t = threadIdx.x;
    if (b < WB) {
        __shared__ float tile[64][65];
        const int tr = b >> 2, tc = b & 3;
        const int k0 = tr * 64, n0 = tc * 64;
        const int r = t >> 6, c = t & 63;
        const float* Wsrc = (k0 < 256) ? (W_l + (size_t)k0 * DD)
                                       : (W_r + (size_t)(k0 - 256) * DD);
#pragma unroll
        for (int i = 0; i < 16; i++) {
            int row = r + i * 4;
            tile[row][c] = Wsrc[(size_t)row * DD + n0 + c];
        }
        __syncthreads();
#pragma unroll
        for (int i = 0; i < 16; i++) {
            int row = r + i * 4;
            Wt[(size_t)(n0 + row) * KK + k0 + c] = f2bf(tile[c][row]);
        }
    } else if (b < WB + HB) {
        int id = (b - WB) * 256 + t;
        int node = id >> 6, seg = (id & 63) * 4;
        float4 v = *(const float4*)(h + (size_t)node * DD + seg);
        us4 o;
        o[0] = f2bf(v.x); o[1] = f2bf(v.y); o[2] = f2bf(v.z); o[3] = f2bf(v.w);
        *(us4*)(Ab + (size_t)node * KK + 256 + seg) = o;
        uint pk = fp8enc(v.x) | (fp8enc(v.y) << 8)
                | (fp8enc(v.z) << 16) | (fp8enc(v.w) << 24);
        *(uint*)(h8 + (size_t)node * DD + seg) = pk;
    } else {
        int e = (b - WB - HB) * 256 + t;
        if (e < NE) rank[e] = atomicAdd(&degi[ei[NE + e]], 1);  // rank = old
    }
}

// ---------------- 2. prefix scan (shuffle-based, 2 syncs) -----------------
__global__ __launch_bounds__(1024) void scan_start(
    const int* __restrict__ degi, int* __restrict__ start,
    float* __restrict__ invdeg) {
    __shared__ int wsum[16];
    __shared__ int woff[16];
    const int t = threadIdx.x, wid = t >> 6, lane = t & 63;
    const int CH = 10;
    const int base = t * CH;
    int sum = 0;
#pragma unroll
    for (int i = 0; i < CH; i++) {
        int idx = base + i;
        if (idx < NN) sum += degi[idx];
    }
    int x = sum;
#pragma unroll
    for (int off = 1; off < 64; off <<= 1) {
        int v = __shfl_up(x, off);
        if (lane >= off) x += v;
    }
    if (lane == 63) wsum[wid] = x;
    __syncthreads();
    if (t == 0) {
        int run = 0;
#pragma unroll
        for (int w = 0; w < 16; w++) { woff[w] = run; run += wsum[w]; }
    }
    __syncthreads();
    int run = woff[wid] + x - sum;
#pragma unroll
    for (int i = 0; i < CH; i++) {
        int idx = base + i;
        if (idx < NN) {
            start[idx]  = run;
            int d = degi[idx];
            invdeg[idx] = 1.0f / fmaxf((float)d, 1.0f);
            run += d;
        }
    }
    if (t == 1023) start[NN] = NE;
}

// ---------------- 3. fill CSR (atomic-free: rank-addressed stores) --------
__global__ __launch_bounds__(256) void fill_csr(
    const int* __restrict__ ei, const int* __restrict__ start,
    const int* __restrict__ rank, int* __restrict__ csr) {
    int e = blockIdx.x * 256 + threadIdx.x;
    if (e >= NE) return;
    csr[start[ei[NE + e]] + rank[e]] = ei[e];
}

// ---------------- 4. gather mean (fp8 reads: 256B/edge, L2-resident) ------
__global__ __launch_bounds__(256) void gather_mean(
    ushort* __restrict__ Ab, const uchar* __restrict__ h8,
    const int* __restrict__ csr,
    const int* __restrict__ start, const float* __restrict__ invdeg) {
    int node = blockIdx.x * 4 + (threadIdx.x >> 6);
    int lane = threadIdx.x & 63;
    if (node >= NN) return;
    int s = start[node], e = start[node + 1];
    const uchar* hp = h8 + lane * 4;
    float a0 = 0.f, a1 = 0.f, a2 = 0.f, a3 = 0.f;
    float b0 = 0.f, b1 = 0.f, b2 = 0.f, b3 = 0.f;
    int j = s;
    for (; j + 4 <= e; j += 4) {
        int s0 = csr[j], s1 = csr[j + 1], s2 = csr[j + 2], s3 = csr[j + 3];
        uint w0 = *(const uint*)(hp + (size_t)s0 * DD);
        uint w1 = *(const uint*)(hp + (size_t)s1 * DD);
        uint w2 = *(const uint*)(hp + (size_t)s2 * DD);
        uint w3 = *(const uint*)(hp + (size_t)s3 * DD);
        a0 += fp8dec(w0 & 0xFF) + fp8dec(w1 & 0xFF);
        a1 += fp8dec((w0 >> 8) & 0xFF) + fp8dec((w1 >> 8) & 0xFF);
        a2 += fp8dec((w0 >> 16) & 0xFF) + fp8dec((w1 >> 16) & 0xFF);
        a3 += fp8dec(w0 >> 24) + fp8dec(w1 >> 24);
        b0 += fp8dec(w2 & 0xFF) + fp8dec(w3 & 0xFF);
        b1 += fp8dec((w2 >> 8) & 0xFF) + fp8dec((w3 >> 8) & 0xFF);
        b2 += fp8dec((w2 >> 16) & 0xFF) + fp8dec((w3 >> 16) & 0xFF);
        b3 += fp8dec(w2 >> 24) + fp8dec(w3 >> 24);
    }
    for (; j < e; j++) {
        uint w0 = *(const uint*)(hp + (size_t)csr[j] * DD);
        a0 += fp8dec(w0 & 0xFF);
        a1 += fp8dec((w0 >> 8) & 0xFF);
        a2 += fp8dec((w0 >> 16) & 0xFF);
        a3 += fp8dec(w0 >> 24);
    }
    float id = invdeg[node];
    us4 m;
    m[0] = f2bf((a0 + b0) * id);
    m[1] = f2bf((a1 + b1) * id);
    m[2] = f2bf((a2 + b2) * id);
    m[3] = f2bf((a3 + b3) * id);
    *(us4*)(Ab + (size_t)node * KK + lane * 4) = m;
}

// ---------------- 5. MFMA GEMM: atomic-free y/c/r via LDS reduce ----------
__global__ __launch_bounds__(256) void gemm_x(
    const ushort* __restrict__ Ab, const ushort* __restrict__ Wt,
    const float* __restrict__ b_l,
    const float* __restrict__ W_rel, const float* __restrict__ W_gate,
    const float* __restrict__ W_root,
    float* __restrict__ xout, float* __restrict__ y,
    float* __restrict__ cvec, float* __restrict__ rvec) {
    __shared__ ushort Asm[2][32][40];
    __shared__ ushort Bsm[2][256][40];
    __shared__ float Ys[4][32], Cs[4][32], Rs[4][32];
    const int t    = threadIdx.x;
    const int row0 = blockIdx.x * 32;
    const int wid  = t >> 6, lane = t & 63;
    const int l15  = lane & 15, g = lane >> 4;

    f32x4 acc[2][4];
#pragma unroll
    for (int fi = 0; fi < 2; fi++)
#pragma unroll
        for (int fj = 0; fj < 4; fj++) acc[fi][fj] = (f32x4)0.f;

    const int  arow = t >> 3, akseg = (t & 7) * 4;
    const bool aok  = (row0 + arow) < NN;
    const ushort* aptr = Ab + (size_t)(row0 + arow) * KK + akseg;
    const ushort* bptr = Wt + (size_t)t * KK;

    us4 areg = {0, 0, 0, 0};
    us8 breg[4];
    if (aok) areg = *(const us4*)(aptr);
#pragma unroll
    for (int jj = 0; jj < 4; jj++) breg[jj] = *(const us8*)(bptr + jj * 8);
    *(us4*)&Asm[0][arow][akseg] = areg;
#pragma unroll
    for (int jj = 0; jj < 4; jj++) *(us8*)&Bsm[0][t][jj * 8] = breg[jj];
    __syncthreads();

    for (int ks = 0; ks < 16; ++ks) {
        const int cur = ks & 1;
        if (ks < 15) {
            const int k0 = (ks + 1) * 32;
            if (aok) areg = *(const us4*)(aptr + k0);
#pragma unroll
            for (int jj = 0; jj < 4; jj++) breg[jj] = *(const us8*)(bptr + k0 + jj * 8);
        }
        short8 af0 = *(const short8*)&Asm[cur][l15][g * 8];
        short8 af1 = *(const short8*)&Asm[cur][16 + l15][g * 8];
#pragma unroll
        for (int fj = 0; fj < 4; fj++) {
            short8 bf = *(const short8*)&Bsm[cur][wid * 64 + fj * 16 + l15][g * 8];
            acc[0][fj] = __builtin_amdgcn_mfma_f32_16x16x32_bf16(af0, bf, acc[0][fj], 0, 0, 0);
            acc[1][fj] = __builtin_amdgcn_mfma_f32_16x16x32_bf16(af1, bf, acc[1][fj], 0, 0, 0);
        }
        if (ks < 15) {
            const int nb = cur ^ 1;
            *(us4*)&Asm[nb][arow][akseg] = areg;
#pragma unroll
            for (int jj = 0; jj < 4; jj++) *(us8*)&Bsm[nb][t][jj * 8] = breg[jj];
        }
        __syncthreads();
    }

    const int wcol0 = wid * 64;
    float bl[4], wl[4], wg[4], wo[4];
#pragma unroll
    for (int fj = 0; fj < 4; fj++) {
        int col = wcol0 + fj * 16 + l15;
        bl[fj] = b_l[col]; wl[fj] = W_rel[col];
        wg[fj] = W_gate[col]; wo[fj] = W_root[col];
    }
#pragma unroll
    for (int fi = 0; fi < 2; fi++) {
#pragma unroll
        for (int r = 0; r < 4; r++) {
            int row = row0 + fi * 16 + g * 4 + r;
            float py = 0.f, pc = 0.f, pr = 0.f;
#pragma unroll
            for (int fj = 0; fj < 4; fj++) {
                float v = fmaxf(acc[fi][fj][r] + bl[fj], 0.f);
                if (row < NN)
                    xout[(size_t)row * DD + wcol0 + fj * 16 + l15] = v;
                py = fmaf(v, wl[fj], py);
                pc = fmaf(v, wg[fj], pc);
                pr = fmaf(v, wo[fj], pr);
            }
#pragma unroll
            for (int off = 1; off < 16; off <<= 1) {
                py += __shfl_xor(py, off);
                pc += __shfl_xor(pc, off);
                pr += __shfl_xor(pr, off);
            }
            if (l15 == 0) {
                int rl = fi * 16 + g * 4 + r;
                Ys[wid][rl] = py; Cs[wid][rl] = pc; Rs[wid][rl] = pr;
            }
        }
    }
    __syncthreads();
    if (t < 32) {
        int row = row0 + t;
        if (row < NN) {
            y[row]    = Ys[0][t] + Ys[1][t] + Ys[2][t] + Ys[3][t];
            cvec[row] = Cs[0][t] + Cs[1][t] + Cs[2][t] + Cs[3][t];
            rvec[row] = Rs[0][t] + Rs[1][t] + Rs[2][t] + Rs[3][t];
        }
    }
}

// ---------------- 6. gather y + score + key -------------------------------
__global__ __launch_bounds__(256) void gather_score(
    const float* __restrict__ y, const float* __restrict__ r,
    const float* __restrict__ b_rel, const int* __restrict__ csr,
    const int* __restrict__ start,
    float* __restrict__ score, uint* __restrict__ key) {
    int gt   = blockIdx.x * 256 + threadIdx.x;
    int node = gt >> 4, l = gt & 15;
    if (node >= NN) return;
    int s = start[node], e = start[node + 1];
    float acc = 0.f;
    for (int j = s + l; j < e; j += 16) acc += y[csr[j]];
#pragma unroll
    for (int o = 8; o; o >>= 1) acc += __shfl_xor(acc, o, 16);
    if (l == 0) {
        float sc = tanhf(acc + b_rel[0] + r[node]);
        score[node] = sc;
        key[node]   = encodeF(sc);
    }
}

// ---------------- 7. radix select v2 (also zeroes reduce counter) ---------
__global__ __launch_bounds__(1024) void radix_select(
    const uint* __restrict__ key, const float* __restrict__ score,
    const float* __restrict__ cvec,
    float* __restrict__ wsc, float* __restrict__ denom,
    uint* __restrict__ counter) {
    __shared__ uint  hist[16][260];
    __shared__ uint  sh_prefix, sh_need;
    __shared__ float wred[16];
    __shared__ uint  tick_s;
    const int t = threadIdx.x, wid = t >> 6, lane = t & 63;
    if (t == 0) counter[0] = 0;          // stream-ordered before reduce_rows

    uint  myk[10];
    float mys[10], myl[10];
#pragma unroll
    for (int i = 0; i < 10; i++) {
        int idx = t + i * 1024;
        if (idx < NN) {
            uint k  = key[idx];
            float s = score[idx];
            myk[i] = k; mys[i] = s; myl[i] = s * cvec[idx];
        } else {
            myk[i] = 0u; mys[i] = 0.f; myl[i] = -INFINITY;
        }
    }

    uint prefix = 0, pmask = 0, need = KSEL;
    float vmax = -INFINITY;
    for (int shift = 24; shift >= 0; shift -= 8) {
        for (int i = lane; i < 256; i += 64) hist[wid][i] = 0;
        if (shift == 0) {
#pragma unroll
            for (int i = 0; i < 10; i++) {
                uint k = myk[i];
                if ((k & pmask) == prefix) atomicAdd(&hist[wid][k & 255], 1u);
                if (k >= prefix) vmax = fmaxf(vmax, myl[i]);
            }
        } else {
#pragma unroll
            for (int i = 0; i < 10; i++) {
                uint k = myk[i];
                if ((k & pmask) == prefix)
                    atomicAdd(&hist[wid][(k >> shift) & 255], 1u);
            }
        }
        __syncthreads();
        if (wid == 0) {
            uint4 a = make_uint4(0u, 0u, 0u, 0u);
#pragma unroll
            for (int w = 0; w < 16; w++) {
                uint4 v = *(const uint4*)&hist[w][lane * 4];
                a.x += v.x; a.y += v.y; a.z += v.z; a.w += v.w;
            }
            uint s3 = a.w, s2 = a.z + s3, s1 = a.y + s2, s0 = a.x + s1;
            uint x = s0;
#pragma unroll
            for (int off = 1; off < 64; off <<= 1) {
                uint v = __shfl_down(x, off);
                if (lane + off < 64) x += v;
            }
            uint excl = x - s0;
            uint hi0 = excl + s0, hi1 = excl + s1;
            uint hi2 = excl + s2, hi3 = excl + s3;
            if (need <= hi0 && need > hi0 - a.x) {
                sh_prefix = prefix | ((uint)(lane * 4 + 0) << shift);
                sh_need   = need - (hi0 - a.x);
            }
            if (need <= hi1 && need > hi1 - a.y) {
                sh_prefix = prefix | ((uint)(lane * 4 + 1) << shift);
                sh_need   = need - (hi1 - a.y);
            }
            if (need <= hi2 && need > hi2 - a.z) {
                sh_prefix = prefix | ((uint)(lane * 4 + 2) << shift);
                sh_need   = need - (hi2 - a.z);
            }
            if (need <= hi3 && need > hi3 - a.w) {
                sh_prefix = prefix | ((uint)(lane * 4 + 3) << shift);
                sh_need   = need - (hi3 - a.w);
            }
        }
        __syncthreads();
        prefix = sh_prefix;
        need   = sh_need;
        pmask |= (0xFFu << shift);
    }
    const uint T      = prefix;
    const uint needEq = need;
#pragma unroll
    for (int o = 32; o; o >>= 1) vmax = fmaxf(vmax, __shfl_xor(vmax, o));
    if (lane == 0) wred[wid] = vmax;
    if (t == 0) tick_s = 0;
    __syncthreads();
    float m = wred[0];
#pragma unroll
    for (int w = 1; w < 16; w++) m = fmaxf(m, wred[w]);
    __syncthreads();
    float dsum = 0.f;
#pragma unroll
    for (int i = 0; i < 10; i++) {
        int idx = t + i * 1024;
        if (idx >= NN) continue;
        uint k = myk[i];
        bool selm = (k > T);
        if (k == T) selm = (atomicAdd(&tick_s, 1u) < needEq);
        float wv = 0.f;
        if (selm) {
            float w = expf(myl[i] - m);
            wv   = w * mys[i];
            dsum += w;
        }
        wsc[idx] = wv;
    }
#pragma unroll
    for (int o = 32; o; o >>= 1) dsum += __shfl_xor(dsum, o);
    if (lane == 0) wred[wid] = dsum;
    __syncthreads();
    if (t == 0) {
        float d = 0.f;
#pragma unroll
        for (int w = 0; w < 16; w++) d += wred[w];
        denom[0] = d;
    }
}

// ---------------- 8. weighted row-sum + last-block finalize ---------------
__global__ __launch_bounds__(256) void reduce_rows(
    const float* __restrict__ x, const float* __restrict__ wsc,
    float* __restrict__ part, uint* __restrict__ counter,
    const float* __restrict__ denom, float* __restrict__ out) {
    __shared__ float red[3][DD];
    __shared__ uint  lastdone;
    const int wave = threadIdx.x >> 6;
    const int lane = threadIdx.x & 63;
    const int row0 = (blockIdx.x * 4 + wave) * 16;
    const float* xp = x + lane * 4;
    float4 acc = make_float4(0.f, 0.f, 0.f, 0.f);
    if (row0 < NN) {
#pragma unroll
        for (int rb = 0; rb < 16; rb += 4) {
            int r0 = row0 + rb;
            float w0 = wsc[r0 + 0], w1 = wsc[r0 + 1];
            float w2 = wsc[r0 + 2], w3 = wsc[r0 + 3];
            float4 v0 = *(const float4*)(xp + (size_t)(r0 + 0) * DD);
            float4 v1 = *(const float4*)(xp + (size_t)(r0 + 1) * DD);
            float4 v2 = *(const float4*)(xp + (size_t)(r0 + 2) * DD);
            float4 v3 = *(const float4*)(xp + (size_t)(r0 + 3) * DD);
            acc.x = fmaf(w0, v0.x, fmaf(w1, v1.x, fmaf(w2, v2.x, fmaf(w3, v3.x, acc.x))));
            acc.y = fmaf(w0, v0.y, fmaf(w1, v1.y, fmaf(w2, v2.y, fmaf(w3, v3.y, acc.y))));
            acc.z = fmaf(w0, v0.z, fmaf(w1, v1.z, fmaf(w2, v2.z, fmaf(w3, v3.z, acc.z))));
            acc.w = fmaf(w0, v0.w, fmaf(w1, v1.w, fmaf(w2, v2.w, fmaf(w3, v3.w, acc.w))));
        }
    }
    if (wave > 0) *(float4*)&red[wave - 1][lane * 4] = acc;
    __syncthreads();
    if (wave == 0) {
#pragma unroll
        for (int w = 0; w < 3; w++) {
            float4 rv = *(float4*)&red[w][lane * 4];
            acc.x += rv.x; acc.y += rv.y; acc.z += rv.z; acc.w += rv.w;
        }
        *(float4*)(part + (size_t)blockIdx.x * DD + lane * 4) = acc;
    }
    __threadfence();
    if (threadIdx.x == 0) lastdone = atomicAdd(counter, 1u);
    __syncthreads();
    if (lastdone == NPART - 1) {
        __threadfence();
        int i = threadIdx.x;
        float s = 0.f;
        for (int b = 0; b < NPART; b++) s += part[(size_t)b * DD + i];
        out[i] = s / denom[0];
    }
}

extern "C" void kernel_launch(void* const* d_in, const int* in_sizes, int n_in,
                              void* d_out, int out_size, void* d_ws, size_t ws_size,
                              hipStream_t stream) {
    const float* h      = (const float*)d_in[0];
    const int*   ei     = (const int*)d_in[1];
    const float* W_l    = (const float*)d_in[2];
    const float* b_l    = (const float*)d_in[3];
    const float* W_r    = (const float*)d_in[4];
    const float* W_rel  = (const float*)d_in[5];
    const float* b_rel  = (const float*)d_in[6];
    const float* W_root = (const float*)d_in[7];
    const float* W_gate = (const float*)d_in[8];
    // b_gate (d_in[9]) cancels in softmax
    float* out = (float*)d_out;

    char* p = (char*)d_ws;
    auto alloc = [&p](size_t bytes) {
        char* q = p;
        p += (bytes + 63) & ~(size_t)63;
        return q;
    };
    ushort* Ab    = (ushort*)alloc((size_t)NN * KK * 2);   // [mean|h] bf16
    uchar*  h8    = (uchar*) alloc((size_t)NN * DD);
    float*  xbuf  = (float*) alloc((size_t)NN * DD * 4);
    ushort* Wt    = (ushort*)alloc((size_t)DD * KK * 2);
    int*    csr   = (int*)   alloc((size_t)NE * 4);
    int*    rank  = (int*)   alloc((size_t)NE * 4);
    int*    start = (int*)   alloc((size_t)(NN + 1) * 4);
    float*  invdeg= (float*) alloc((size_t)NN * 4);
    float*  score = (float*) alloc((size_t)NN * 4);
    uint*   key   = (uint*)  alloc((size_t)NN * 4);
    float*  wsc   = (float*) alloc((size_t)NN * 4);
    float*  denom = (float*) alloc(64);
    float*  part  = (float*) alloc((size_t)NPART * DD * 4);
    float*  y     = (float*) alloc((size_t)NN * 4);
    float*  cbuf  = (float*) alloc((size_t)NN * 4);
    float*  rbuf  = (float*) alloc((size_t)NN * 4);
    uint*   cnt   = (uint*)  alloc(64);              // zeroed in radix_select
    // ---- zero-initialized region: degi only (40000 B) ----
    int*    degi  = (int*)   alloc((size_t)NN * 4);

    zero_bufs   <<<(ZQUADS + 255) / 256, 256, 0, stream>>>((float4*)degi);
    prep        <<<WB + HB + DB, 256, 0, stream>>>(h, W_l, W_r, ei,
                                                   Ab, h8, Wt, degi, rank);
    scan_start  <<<1, 1024, 0, stream>>>(degi, start, invdeg);
    fill_csr    <<<(NE + 255) / 256, 256, 0, stream>>>(ei, start, rank, csr);
    gather_mean <<<(NN + 3) / 4, 256, 0, stream>>>(Ab, h8, csr, start, invdeg);
    gemm_x      <<<(NN + 31) / 32, 256, 0, stream>>>(Ab, Wt, b_l,
                                                     W_rel, W_gate, W_root,
                                                     xbuf, y, cbuf, rbuf);
    gather_score<<<(NN * 16 + 255) / 256, 256, 0, stream>>>(y, rbuf, b_rel, csr,
                                                            start, score, key);
    radix_select<<<1, 1024, 0, stream>>>(key, score, cbuf, wsc, denom, cnt);
    reduce_rows <<<NPART, 256, 0, stream>>>(xbuf, wsc, part, cnt, denom, out);
    (void)n_in; (void)in_sizes; (void)out_size; (void)ws_size;
}